// Round 1
// baseline (1221.163 us; speedup 1.0000x reference)
//
#include <hip/hip_runtime.h>

#define N_NODES 50000
#define N_EDGES 800000
#define D_IN 128
#define D_HID 256
#define D_OUT 256

// ---------------- CSR build ----------------

__global__ void hist_kernel(const int* __restrict__ dst, int* __restrict__ cnt) {
    int e = blockIdx.x * blockDim.x + threadIdx.x;
    if (e < N_EDGES) atomicAdd(&cnt[dst[e]], 1);
}

__global__ __launch_bounds__(1024) void scan_kernel(const int* __restrict__ cnt,
                                                    int* __restrict__ row_ptr,
                                                    int* __restrict__ cursor,
                                                    float* __restrict__ inv_deg) {
    __shared__ int buf[1024];
    int tid = threadIdx.x;
    const int per = (N_NODES + 1023) / 1024;  // 49
    int start = tid * per;
    int end = start + per;
    if (end > N_NODES) end = N_NODES;
    int local = 0;
    for (int i = start; i < end; ++i) local += cnt[i];
    buf[tid] = local;
    __syncthreads();
    for (int off = 1; off < 1024; off <<= 1) {
        int v = buf[tid];
        int add = (tid >= off) ? buf[tid - off] : 0;
        __syncthreads();
        buf[tid] = v + add;
        __syncthreads();
    }
    int run = buf[tid] - local;  // exclusive base for this chunk
    for (int i = start; i < end; ++i) {
        int c = cnt[i];
        row_ptr[i] = run;
        cursor[i] = run;
        inv_deg[i] = 1.0f / (float)max(c, 1);
        run += c;
    }
    if (start < N_NODES && end == N_NODES) row_ptr[N_NODES] = run;
}

__global__ void fill_kernel(const int* __restrict__ src, const int* __restrict__ dst,
                            int* __restrict__ cursor, int* __restrict__ srcs) {
    int e = blockIdx.x * blockDim.x + threadIdx.x;
    if (e < N_EDGES) {
        int pos = atomicAdd(&cursor[dst[e]], 1);
        srcs[pos] = src[e];
    }
}

// ---------------- mean aggregation (CSR gather-sum) ----------------

template <int D>
__global__ void agg_kernel(const float* __restrict__ feat,
                           const int* __restrict__ row_ptr,
                           const int* __restrict__ srcs,
                           const float* __restrict__ inv_deg,
                           float* __restrict__ out) {
    int n = blockIdx.x;
    int tid = threadIdx.x;
    int beg = row_ptr[n], end = row_ptr[n + 1];
    float acc = 0.f;
    for (int e = beg; e < end; ++e) {
        int s = srcs[e];
        acc += feat[(long)s * D + tid];
    }
    out[(long)n * D + tid] = acc * inv_deg[n];
}

// ---------------- layer 1: h1 = relu(x@Ws1 + agg1@Wn1 + b1) ----------------

__global__ __launch_bounds__(256) void gemm1_kernel(const float* __restrict__ x,
                                                    const float* __restrict__ agg1,
                                                    const float* __restrict__ Ws,
                                                    const float* __restrict__ Wn,
                                                    const float* __restrict__ b,
                                                    float* __restrict__ h1) {
    const int ROWS = 16;
    __shared__ float xs[ROWS][D_IN];
    __shared__ float as_[ROWS][D_IN];
    int tid = threadIdx.x;
    int base = blockIdx.x * ROWS;
    for (int i = 0; i < ROWS * D_IN / 256; ++i) {
        int idx = i * 256 + tid;
        int r = idx >> 7, k = idx & 127;
        xs[r][k] = x[(long)(base + r) * D_IN + k];
        as_[r][k] = agg1[(long)(base + r) * D_IN + k];
    }
    __syncthreads();
    float acc[ROWS];
    float bv = b[tid];
#pragma unroll
    for (int r = 0; r < ROWS; ++r) acc[r] = bv;
    for (int k = 0; k < D_IN; ++k) {
        float ws = Ws[k * D_HID + tid];
        float wn = Wn[k * D_HID + tid];
#pragma unroll
        for (int r = 0; r < ROWS; ++r)
            acc[r] += xs[r][k] * ws + as_[r][k] * wn;
    }
#pragma unroll
    for (int r = 0; r < ROWS; ++r)
        h1[(long)(base + r) * D_HID + tid] = fmaxf(acc[r], 0.f);
}

// ------- layer 2 fused with residual + MLP head:
// h2 = h1@Ws2 + agg2@Wn2 + b2 + x@Wres ; out = h2@Wmlp + bmlp -------

__global__ __launch_bounds__(256) void gemm2_kernel(const float* __restrict__ x,
                                                    const float* __restrict__ h1,
                                                    const float* __restrict__ agg2,
                                                    const float* __restrict__ Ws2,
                                                    const float* __restrict__ Wn2,
                                                    const float* __restrict__ b2,
                                                    const float* __restrict__ Wres,
                                                    const float* __restrict__ Wmlp,
                                                    const float* __restrict__ bmlp,
                                                    float* __restrict__ out) {
    const int ROWS = 16;
    __shared__ float h1s[ROWS][D_HID];
    __shared__ float a2s[ROWS][D_HID];
    __shared__ float xsr[ROWS][D_IN];
    __shared__ float red[4][ROWS][2];
    int tid = threadIdx.x;
    int base = blockIdx.x * ROWS;
    for (int i = 0; i < ROWS * D_HID / 256; ++i) {
        int idx = i * 256 + tid;
        int r = idx >> 8, k = idx & 255;
        h1s[r][k] = h1[(long)(base + r) * D_HID + k];
        a2s[r][k] = agg2[(long)(base + r) * D_HID + k];
    }
    for (int i = 0; i < ROWS * D_IN / 256; ++i) {
        int idx = i * 256 + tid;
        int r = idx >> 7, k = idx & 127;
        xsr[r][k] = x[(long)(base + r) * D_IN + k];
    }
    __syncthreads();
    float acc[ROWS];
    float bv = b2[tid];
#pragma unroll
    for (int r = 0; r < ROWS; ++r) acc[r] = bv;
    for (int k = 0; k < D_HID; ++k) {
        float ws = Ws2[k * D_OUT + tid];
        float wn = Wn2[k * D_OUT + tid];
#pragma unroll
        for (int r = 0; r < ROWS; ++r)
            acc[r] += h1s[r][k] * ws + a2s[r][k] * wn;
    }
    for (int k = 0; k < D_IN; ++k) {
        float wr = Wres[k * D_OUT + tid];
#pragma unroll
        for (int r = 0; r < ROWS; ++r)
            acc[r] += xsr[r][k] * wr;
    }
    // MLP head: out[base+r][j] = sum_c acc_c[r] * Wmlp[c*2+j] + bmlp[j]
    float wm0 = Wmlp[tid * 2 + 0];
    float wm1 = Wmlp[tid * 2 + 1];
    int wave = tid >> 6;
    int lane = tid & 63;
#pragma unroll
    for (int r = 0; r < ROWS; ++r) {
        float v0 = acc[r] * wm0;
        float v1 = acc[r] * wm1;
        for (int off = 32; off > 0; off >>= 1) {
            v0 += __shfl_down(v0, off);
            v1 += __shfl_down(v1, off);
        }
        if (lane == 0) { red[wave][r][0] = v0; red[wave][r][1] = v1; }
    }
    __syncthreads();
    if (tid < ROWS * 2) {
        int r = tid >> 1, j = tid & 1;
        float s = red[0][r][j] + red[1][r][j] + red[2][r][j] + red[3][r][j];
        out[(long)(base + r) * 2 + j] = s + bmlp[j];
    }
}

// ---------------- launch ----------------

extern "C" void kernel_launch(void* const* d_in, const int* in_sizes, int n_in,
                              void* d_out, int out_size, void* d_ws, size_t ws_size,
                              hipStream_t stream) {
    const float* x    = (const float*)d_in[0];
    const int*   src  = (const int*)d_in[1];
    const int*   dst  = (const int*)d_in[2];
    const float* Ws1  = (const float*)d_in[3];
    const float* Wn1  = (const float*)d_in[4];
    const float* b1   = (const float*)d_in[5];
    const float* Ws2  = (const float*)d_in[6];
    const float* Wn2  = (const float*)d_in[7];
    const float* b2   = (const float*)d_in[8];
    const float* Wres = (const float*)d_in[9];
    const float* Wmlp = (const float*)d_in[10];
    const float* bmlp = (const float*)d_in[11];
    float* out = (float*)d_out;

    char* ws = (char*)d_ws;
    size_t off = 0;
    auto alloc = [&](size_t bytes) {
        void* p = ws + off;
        off += (bytes + 255) & ~(size_t)255;
        return p;
    };
    int*   cnt     = (int*)alloc((size_t)N_NODES * 4);
    int*   row_ptr = (int*)alloc((size_t)(N_NODES + 1) * 4);
    int*   cursor  = (int*)alloc((size_t)N_NODES * 4);
    float* inv_deg = (float*)alloc((size_t)N_NODES * 4);
    int*   srcs    = (int*)alloc((size_t)N_EDGES * 4);
    // aggbuf holds agg1 (D_IN wide) for layer 1, then is overwritten by agg2 (D_HID wide)
    float* aggbuf  = (float*)alloc((size_t)N_NODES * D_HID * 4);
    float* h1      = (float*)alloc((size_t)N_NODES * D_HID * 4);

    hipMemsetAsync(cnt, 0, (size_t)N_NODES * 4, stream);
    hist_kernel<<<(N_EDGES + 255) / 256, 256, 0, stream>>>(dst, cnt);
    scan_kernel<<<1, 1024, 0, stream>>>(cnt, row_ptr, cursor, inv_deg);
    fill_kernel<<<(N_EDGES + 255) / 256, 256, 0, stream>>>(src, dst, cursor, srcs);
    agg_kernel<D_IN><<<N_NODES, D_IN, 0, stream>>>(x, row_ptr, srcs, inv_deg, aggbuf);
    gemm1_kernel<<<N_NODES / 16, 256, 0, stream>>>(x, aggbuf, Ws1, Wn1, b1, h1);
    agg_kernel<D_HID><<<N_NODES, D_HID, 0, stream>>>(h1, row_ptr, srcs, inv_deg, aggbuf);
    gemm2_kernel<<<N_NODES / 16, 256, 0, stream>>>(x, h1, aggbuf, Ws2, Wn2, b2, Wres,
                                                   Wmlp, bmlp, out);
}

// Round 2
// 582.934 us; speedup vs baseline: 2.0949x; 2.0949x over previous
//
#include <hip/hip_runtime.h>

#define N_NODES 50000
#define N_EDGES 800000
#define D_IN 128
#define D_HID 256
#define D_OUT 256

using short8 = __attribute__((ext_vector_type(8))) short;
using f32x4  = __attribute__((ext_vector_type(4))) float;

__device__ inline unsigned short f2bf(float f) {
    unsigned u = __float_as_uint(f);
    u += 0x7fff + ((u >> 16) & 1);
    return (unsigned short)(u >> 16);
}
__device__ inline float bf2f(unsigned v16) {
    return __uint_as_float(v16 << 16);
}

// ---------------- CSR build ----------------

__global__ void hist_kernel(const int* __restrict__ dst, int* __restrict__ cnt) {
    int e = blockIdx.x * blockDim.x + threadIdx.x;
    if (e < N_EDGES) atomicAdd(&cnt[dst[e]], 1);
}

__global__ __launch_bounds__(1024) void scan_kernel(const int* __restrict__ cnt,
                                                    int* __restrict__ row_ptr,
                                                    int* __restrict__ cursor,
                                                    float* __restrict__ inv_deg) {
    __shared__ int buf[1024];
    int tid = threadIdx.x;
    const int per = (N_NODES + 1023) / 1024;  // 49
    int start = tid * per;
    int end = start + per;
    if (end > N_NODES) end = N_NODES;
    int local = 0;
    for (int i = start; i < end; ++i) local += cnt[i];
    buf[tid] = local;
    __syncthreads();
    for (int off = 1; off < 1024; off <<= 1) {
        int v = buf[tid];
        int add = (tid >= off) ? buf[tid - off] : 0;
        __syncthreads();
        buf[tid] = v + add;
        __syncthreads();
    }
    int run = buf[tid] - local;  // exclusive base for this chunk
    for (int i = start; i < end; ++i) {
        int c = cnt[i];
        row_ptr[i] = run;
        cursor[i] = run;
        inv_deg[i] = 1.0f / (float)max(c, 1);
        run += c;
    }
    if (start < N_NODES && end == N_NODES) row_ptr[N_NODES] = run;
}

__global__ void fill_kernel(const int* __restrict__ src, const int* __restrict__ dst,
                            int* __restrict__ cursor, int* __restrict__ srcs) {
    int e = blockIdx.x * blockDim.x + threadIdx.x;
    if (e < N_EDGES) {
        int pos = atomicAdd(&cursor[dst[e]], 1);
        srcs[pos] = src[e];
    }
}

// ---------------- conversions ----------------

// x (fp32) -> bf16 into Acat1 cols [0,128) and Acat2 cols [512,640)
__global__ void convx_kernel(const float* __restrict__ x,
                             unsigned short* __restrict__ A1,
                             unsigned short* __restrict__ A2) {
    int idx = blockIdx.x * 256 + threadIdx.x;
    if (idx >= N_NODES * D_IN) return;
    int n = idx >> 7, k = idx & 127;
    unsigned short b = f2bf(x[idx]);
    A1[(long)n * 256 + k] = b;
    A2[(long)n * 640 + 512 + k] = b;
}

// Wt1[j][k] (256x256): k<128 -> Ws1[k][j], else Wn1[k-128][j]
__global__ void wconv1_kernel(const float* __restrict__ Ws, const float* __restrict__ Wn,
                              unsigned short* __restrict__ Wt) {
    int j = blockIdx.x;
    for (int k = threadIdx.x; k < 256; k += 256) {
        float v = (k < 128) ? Ws[k * 256 + j] : Wn[(k - 128) * 256 + j];
        Wt[j * 256 + k] = f2bf(v);
    }
}

// Wt2[j][k] (256x640): k<256 Ws2, k<512 Wn2, else Wres
__global__ void wconv2_kernel(const float* __restrict__ Ws, const float* __restrict__ Wn,
                              const float* __restrict__ Wr,
                              unsigned short* __restrict__ Wt) {
    int j = blockIdx.x;
    for (int k = threadIdx.x; k < 640; k += 256) {
        float v = (k < 256) ? Ws[k * 256 + j]
                : (k < 512) ? Wn[(k - 256) * 256 + j]
                            : Wr[(k - 512) * 256 + j];
        Wt[j * 640 + k] = f2bf(v);
    }
}

// ---------------- mean aggregation ----------------

// agg1: gather fp32 x rows, write bf16 into Acat1 cols [128,256)
__global__ void agg1_kernel(const float* __restrict__ x,
                            const int* __restrict__ row_ptr,
                            const int* __restrict__ srcs,
                            const float* __restrict__ inv_deg,
                            unsigned short* __restrict__ A1) {
    int n = blockIdx.x;
    int tid = threadIdx.x;  // 128
    int beg = row_ptr[n], end = row_ptr[n + 1];
    float acc = 0.f;
    int e = beg;
    for (; e + 1 < end; e += 2) {
        int s0 = srcs[e], s1 = srcs[e + 1];
        acc += x[(long)s0 * D_IN + tid] + x[(long)s1 * D_IN + tid];
    }
    if (e < end) acc += x[(long)srcs[e] * D_IN + tid];
    A1[(long)n * 256 + 128 + tid] = f2bf(acc * inv_deg[n]);
}

// agg2: gather bf16 h1 rows (Acat2 cols [0,256)), write bf16 into Acat2 cols [256,512)
__global__ void agg2_kernel(unsigned short* __restrict__ A2,
                            const int* __restrict__ row_ptr,
                            const int* __restrict__ srcs,
                            const float* __restrict__ inv_deg) {
    int n = blockIdx.x;
    int tid = threadIdx.x;  // 128 threads, 2 cols each
    int beg = row_ptr[n], end = row_ptr[n + 1];
    float a0 = 0.f, a1 = 0.f;
    int e = beg;
    for (; e + 1 < end; e += 2) {
        int s0 = srcs[e], s1 = srcs[e + 1];
        unsigned v0 = ((const unsigned*)(A2 + (long)s0 * 640))[tid];
        unsigned v1 = ((const unsigned*)(A2 + (long)s1 * 640))[tid];
        a0 += bf2f(v0 & 0xffffu) + bf2f(v1 & 0xffffu);
        a1 += bf2f(v0 >> 16) + bf2f(v1 >> 16);
    }
    if (e < end) {
        unsigned v = ((const unsigned*)(A2 + (long)srcs[e] * 640))[tid];
        a0 += bf2f(v & 0xffffu);
        a1 += bf2f(v >> 16);
    }
    float inv = inv_deg[n];
    unsigned o = (unsigned)f2bf(a0 * inv) | ((unsigned)f2bf(a1 * inv) << 16);
    ((unsigned*)(A2 + (long)n * 640 + 256))[tid] = o;
}

// ---------------- MFMA GEMM: out[row][col] = A[row][:] . Bt[col][:] + bias ----------------
// A: [N_NODES][K] bf16, Bt: [256][K] bf16. Block tile 128x128, 4 waves of 64x64.

template <int K, bool RELU>
__global__ __launch_bounds__(256) void mfma_gemm_kernel(
    const unsigned short* __restrict__ A, const unsigned short* __restrict__ Bt,
    const float* __restrict__ bias, unsigned short* __restrict__ out, int outStride) {
    int lane = threadIdx.x & 63;
    int wid = threadIdx.x >> 6;
    int rb = blockIdx.x * 128 + (wid >> 1) * 64;
    int cb = blockIdx.y * 128 + (wid & 1) * 64;
    int l15 = lane & 15;
    int kg = (lane >> 4) * 8;
    f32x4 acc[4][4] = {};
    for (int kc = 0; kc < K; kc += 32) {
        short8 a[4], b[4];
#pragma unroll
        for (int i = 0; i < 4; ++i) {
            int r = rb + 16 * i + l15;
            if (r < N_NODES)
                a[i] = *(const short8*)(A + (long)r * K + kc + kg);
            else
                a[i] = (short8)(short)0;
            b[i] = *(const short8*)(Bt + (long)(cb + 16 * i + l15) * K + kc + kg);
        }
#pragma unroll
        for (int i = 0; i < 4; ++i)
#pragma unroll
            for (int j = 0; j < 4; ++j)
                acc[i][j] = __builtin_amdgcn_mfma_f32_16x16x32_bf16(a[i], b[j], acc[i][j], 0, 0, 0);
    }
    // C/D layout: col = lane&15, row = (lane>>4)*4 + reg   [m89-verified]
#pragma unroll
    for (int j = 0; j < 4; ++j) {
        int c = cb + 16 * j + l15;
        float bv = bias[c];
#pragma unroll
        for (int i = 0; i < 4; ++i) {
            int rbase = rb + 16 * i + (lane >> 4) * 4;
#pragma unroll
            for (int r = 0; r < 4; ++r) {
                int row = rbase + r;
                if (row < N_NODES) {
                    float v = acc[i][j][r] + bv;
                    if (RELU) v = fmaxf(v, 0.f);
                    out[(long)row * outStride + c] = f2bf(v);
                }
            }
        }
    }
}

// ---------------- MLP head: out[n][j] = sum_k h2[n][k]*Wmlp[k][j] + bmlp[j] ----------------

__global__ __launch_bounds__(256) void head_kernel(const unsigned short* __restrict__ h2,
                                                   const float* __restrict__ Wmlp,
                                                   const float* __restrict__ bmlp,
                                                   float* __restrict__ out) {
    int n = blockIdx.x * 4 + (threadIdx.x >> 6);
    int lane = threadIdx.x & 63;
    const unsigned* p = (const unsigned*)(h2 + (long)n * 256 + lane * 4);
    unsigned v0 = p[0], v1 = p[1];
    float f0 = bf2f(v0 & 0xffffu), f1 = bf2f(v0 >> 16);
    float f2 = bf2f(v1 & 0xffffu), f3 = bf2f(v1 >> 16);
    int k = lane * 4;
    float p0 = f0 * Wmlp[k * 2]       + f1 * Wmlp[(k + 1) * 2]
             + f2 * Wmlp[(k + 2) * 2] + f3 * Wmlp[(k + 3) * 2];
    float p1 = f0 * Wmlp[k * 2 + 1]       + f1 * Wmlp[(k + 1) * 2 + 1]
             + f2 * Wmlp[(k + 2) * 2 + 1] + f3 * Wmlp[(k + 3) * 2 + 1];
    for (int off = 32; off; off >>= 1) {
        p0 += __shfl_down(p0, off);
        p1 += __shfl_down(p1, off);
    }
    if (lane == 0) {
        out[(long)n * 2]     = p0 + bmlp[0];
        out[(long)n * 2 + 1] = p1 + bmlp[1];
    }
}

// ---------------- launch ----------------

extern "C" void kernel_launch(void* const* d_in, const int* in_sizes, int n_in,
                              void* d_out, int out_size, void* d_ws, size_t ws_size,
                              hipStream_t stream) {
    const float* x    = (const float*)d_in[0];
    const int*   src  = (const int*)d_in[1];
    const int*   dst  = (const int*)d_in[2];
    const float* Ws1  = (const float*)d_in[3];
    const float* Wn1  = (const float*)d_in[4];
    const float* b1   = (const float*)d_in[5];
    const float* Ws2  = (const float*)d_in[6];
    const float* Wn2  = (const float*)d_in[7];
    const float* b2   = (const float*)d_in[8];
    const float* Wres = (const float*)d_in[9];
    const float* Wmlp = (const float*)d_in[10];
    const float* bmlp = (const float*)d_in[11];
    float* out = (float*)d_out;

    char* ws = (char*)d_ws;
    size_t off = 0;
    auto alloc = [&](size_t bytes) {
        void* p = ws + off;
        off += (bytes + 255) & ~(size_t)255;
        return p;
    };
    int*            cnt     = (int*)alloc((size_t)N_NODES * 4);
    int*            row_ptr = (int*)alloc((size_t)(N_NODES + 1) * 4);
    int*            cursor  = (int*)alloc((size_t)N_NODES * 4);
    float*          inv_deg = (float*)alloc((size_t)N_NODES * 4);
    int*            srcs    = (int*)alloc((size_t)N_EDGES * 4);
    unsigned short* A1      = (unsigned short*)alloc((size_t)N_NODES * 256 * 2);  // [x|agg1]; later h2
    unsigned short* A2      = (unsigned short*)alloc((size_t)N_NODES * 640 * 2);  // [h1|agg2|x]
    unsigned short* Wt1     = (unsigned short*)alloc((size_t)256 * 256 * 2);
    unsigned short* Wt2     = (unsigned short*)alloc((size_t)256 * 640 * 2);

    hipMemsetAsync(cnt, 0, (size_t)N_NODES * 4, stream);
    hist_kernel<<<(N_EDGES + 255) / 256, 256, 0, stream>>>(dst, cnt);
    scan_kernel<<<1, 1024, 0, stream>>>(cnt, row_ptr, cursor, inv_deg);
    fill_kernel<<<(N_EDGES + 255) / 256, 256, 0, stream>>>(src, dst, cursor, srcs);
    convx_kernel<<<(N_NODES * D_IN + 255) / 256, 256, 0, stream>>>(x, A1, A2);
    wconv1_kernel<<<256, 256, 0, stream>>>(Ws1, Wn1, Wt1);
    wconv2_kernel<<<256, 256, 0, stream>>>(Ws2, Wn2, Wres, Wt2);
    agg1_kernel<<<N_NODES, 128, 0, stream>>>(x, row_ptr, srcs, inv_deg, A1);

    dim3 ggrid((N_NODES + 127) / 128, 2);
    // layer 1: h1 = relu([x|agg1] @ Wt1^T + b1) -> Acat2 cols [0,256)
    mfma_gemm_kernel<256, true><<<ggrid, 256, 0, stream>>>(A1, Wt1, b1, A2, 640);
    agg2_kernel<<<N_NODES, 128, 0, stream>>>(A2, row_ptr, srcs, inv_deg);
    // layer 2: h2 = [h1|agg2|x] @ Wt2^T + b2 -> A1 (reused as h2 buffer, stride 256)
    mfma_gemm_kernel<640, false><<<ggrid, 256, 0, stream>>>(A2, Wt2, b2, A1, 256);
    head_kernel<<<N_NODES / 4, 256, 0, stream>>>(A1, Wmlp, bmlp, out);
}

// Round 5
// 463.857 us; speedup vs baseline: 2.6326x; 1.2567x over previous
//
#include <hip/hip_runtime.h>

#define N_NODES 50000
#define N_EDGES 800000
#define D_IN 128
#define D_HID 256
#define D_OUT 256

#define SCAN_BLOCKS ((N_NODES + 255) / 256)  // 196

using short8 = __attribute__((ext_vector_type(8))) short;
using f32x4  = __attribute__((ext_vector_type(4))) float;

__device__ inline unsigned short f2bf(float f) {
    unsigned u = __float_as_uint(f);
    u += 0x7fff + ((u >> 16) & 1);
    return (unsigned short)(u >> 16);
}
__device__ inline float bf2f(unsigned v16) {
    return __uint_as_float(v16 << 16);
}

// ---------------- CSR build ----------------

__global__ void hist_kernel(const int* __restrict__ dst, int* __restrict__ cnt) {
    int e = blockIdx.x * blockDim.x + threadIdx.x;
    if (e < N_EDGES) atomicAdd(&cnt[dst[e]], 1);
}

// stage 1: per-block sums of cnt
__global__ __launch_bounds__(256) void scan1_kernel(const int* __restrict__ cnt,
                                                    int* __restrict__ blocksum) {
    int i = blockIdx.x * 256 + threadIdx.x;
    int v = (i < N_NODES) ? cnt[i] : 0;
    int lane = threadIdx.x & 63, wid = threadIdx.x >> 6;
    for (int off = 32; off; off >>= 1) v += __shfl_down(v, off);
    __shared__ int ws[4];
    if (lane == 0) ws[wid] = v;
    __syncthreads();
    if (threadIdx.x == 0) blocksum[blockIdx.x] = ws[0] + ws[1] + ws[2] + ws[3];
}

// stage 2: exclusive scan of the 196 block sums (single block)
__global__ __launch_bounds__(256) void scan2_kernel(const int* __restrict__ blocksum,
                                                    int* __restrict__ blockoff) {
    int tid = threadIdx.x;
    int lane = tid & 63, wid = tid >> 6;
    int v = (tid < SCAN_BLOCKS) ? blocksum[tid] : 0;
    int inc = v;
    for (int off = 1; off < 64; off <<= 1) {
        int u = __shfl_up(inc, off);
        if (lane >= off) inc += u;
    }
    __shared__ int ws[4];
    if (lane == 63) ws[wid] = inc;
    __syncthreads();
    int base = 0;
    for (int w = 0; w < wid; ++w) base += ws[w];
    if (tid < SCAN_BLOCKS) blockoff[tid] = base + inc - v;  // exclusive
}

// stage 3: intra-block exclusive scan + block offset -> row_ptr / cursor / inv_deg
__global__ __launch_bounds__(256) void scan3_kernel(const int* __restrict__ cnt,
                                                    const int* __restrict__ blockoff,
                                                    int* __restrict__ row_ptr,
                                                    int* __restrict__ cursor,
                                                    float* __restrict__ inv_deg) {
    int i = blockIdx.x * 256 + threadIdx.x;
    int c = (i < N_NODES) ? cnt[i] : 0;
    int lane = threadIdx.x & 63, wid = threadIdx.x >> 6;
    int inc = c;
    for (int off = 1; off < 64; off <<= 1) {
        int u = __shfl_up(inc, off);
        if (lane >= off) inc += u;
    }
    __shared__ int ws[4];
    if (lane == 63) ws[wid] = inc;
    __syncthreads();
    int base = blockoff[blockIdx.x];
    for (int w = 0; w < wid; ++w) base += ws[w];
    if (i < N_NODES) {
        int pos = base + inc - c;
        row_ptr[i] = pos;
        cursor[i] = pos;
        inv_deg[i] = 1.0f / (float)max(c, 1);
    }
    if (i == 0) row_ptr[N_NODES] = N_EDGES;
}

__global__ void fill_kernel(const int* __restrict__ src, const int* __restrict__ dst,
                            int* __restrict__ cursor, int* __restrict__ srcs) {
    int e = blockIdx.x * blockDim.x + threadIdx.x;
    if (e < N_EDGES) {
        int pos = atomicAdd(&cursor[dst[e]], 1);
        srcs[pos] = src[e];
    }
}

// ---------------- conversions ----------------

// x (fp32) -> bf16 into Acat1 cols [0,128) and Acat2 cols [512,640)
__global__ void convx_kernel(const float* __restrict__ x,
                             unsigned short* __restrict__ A1,
                             unsigned short* __restrict__ A2) {
    int idx = blockIdx.x * 256 + threadIdx.x;
    if (idx >= N_NODES * D_IN) return;
    int n = idx >> 7, k = idx & 127;
    unsigned short b = f2bf(x[idx]);
    A1[(long)n * 256 + k] = b;
    A2[(long)n * 640 + 512 + k] = b;
}

// Wt1[j][k] (256x256): k<128 -> Ws1[k][j], else Wn1[k-128][j]
__global__ void wconv1_kernel(const float* __restrict__ Ws, const float* __restrict__ Wn,
                              unsigned short* __restrict__ Wt) {
    int j = blockIdx.x;
    for (int k = threadIdx.x; k < 256; k += 256) {
        float v = (k < 128) ? Ws[k * 256 + j] : Wn[(k - 128) * 256 + j];
        Wt[j * 256 + k] = f2bf(v);
    }
}

// Wt2[j][k] (256x640): k<256 Ws2, k<512 Wn2, else Wres
__global__ void wconv2_kernel(const float* __restrict__ Ws, const float* __restrict__ Wn,
                              const float* __restrict__ Wr,
                              unsigned short* __restrict__ Wt) {
    int j = blockIdx.x;
    for (int k = threadIdx.x; k < 640; k += 256) {
        float v = (k < 256) ? Ws[k * 256 + j]
                : (k < 512) ? Wn[(k - 256) * 256 + j]
                            : Wr[(k - 512) * 256 + j];
        Wt[j * 640 + k] = f2bf(v);
    }
}

// ---------------- mean aggregation ----------------

// agg1: gather fp32 x rows, write bf16 into Acat1 cols [128,256)
__global__ void agg1_kernel(const float* __restrict__ x,
                            const int* __restrict__ row_ptr,
                            const int* __restrict__ srcs,
                            const float* __restrict__ inv_deg,
                            unsigned short* __restrict__ A1) {
    int n = blockIdx.x;
    int tid = threadIdx.x;  // 128
    int beg = row_ptr[n], end = row_ptr[n + 1];
    float acc = 0.f;
    int e = beg;
    for (; e + 1 < end; e += 2) {
        int s0 = srcs[e], s1 = srcs[e + 1];
        acc += x[(long)s0 * D_IN + tid] + x[(long)s1 * D_IN + tid];
    }
    if (e < end) acc += x[(long)srcs[e] * D_IN + tid];
    A1[(long)n * 256 + 128 + tid] = f2bf(acc * inv_deg[n]);
}

// agg2: gather bf16 h1 rows (Acat2 cols [0,256)), write bf16 into Acat2 cols [256,512)
__global__ void agg2_kernel(unsigned short* __restrict__ A2,
                            const int* __restrict__ row_ptr,
                            const int* __restrict__ srcs,
                            const float* __restrict__ inv_deg) {
    int n = blockIdx.x;
    int tid = threadIdx.x;  // 128 threads, 2 cols each
    int beg = row_ptr[n], end = row_ptr[n + 1];
    float a0 = 0.f, a1 = 0.f;
    int e = beg;
    for (; e + 1 < end; e += 2) {
        int s0 = srcs[e], s1 = srcs[e + 1];
        unsigned v0 = ((const unsigned*)(A2 + (long)s0 * 640))[tid];
        unsigned v1 = ((const unsigned*)(A2 + (long)s1 * 640))[tid];
        a0 += bf2f(v0 & 0xffffu) + bf2f(v1 & 0xffffu);
        a1 += bf2f(v0 >> 16) + bf2f(v1 >> 16);
    }
    if (e < end) {
        unsigned v = ((const unsigned*)(A2 + (long)srcs[e] * 640))[tid];
        a0 += bf2f(v & 0xffffu);
        a1 += bf2f(v >> 16);
    }
    float inv = inv_deg[n];
    unsigned o = (unsigned)f2bf(a0 * inv) | ((unsigned)f2bf(a1 * inv) << 16);
    ((unsigned*)(A2 + (long)n * 640 + 256))[tid] = o;
}

// ---------------- MFMA GEMM: out[row][col] = A[row][:] . Bt[col][:] + bias ----------------
// A: [N_NODES][K] bf16, Bt: [256][K] bf16. Block tile 128x128, 4 waves of 64x64.

template <int K, bool RELU>
__global__ __launch_bounds__(256) void mfma_gemm_kernel(
    const unsigned short* __restrict__ A, const unsigned short* __restrict__ Bt,
    const float* __restrict__ bias, unsigned short* __restrict__ out, int outStride) {
    int lane = threadIdx.x & 63;
    int wid = threadIdx.x >> 6;
    int rb = blockIdx.x * 128 + (wid >> 1) * 64;
    int cb = blockIdx.y * 128 + (wid & 1) * 64;
    int l15 = lane & 15;
    int kg = (lane >> 4) * 8;
    f32x4 acc[4][4] = {};
    for (int kc = 0; kc < K; kc += 32) {
        short8 a[4], b[4];
#pragma unroll
        for (int i = 0; i < 4; ++i) {
            int r = rb + 16 * i + l15;
            if (r < N_NODES)
                a[i] = *(const short8*)(A + (long)r * K + kc + kg);
            else
                a[i] = (short8)(short)0;
            b[i] = *(const short8*)(Bt + (long)(cb + 16 * i + l15) * K + kc + kg);
        }
#pragma unroll
        for (int i = 0; i < 4; ++i)
#pragma unroll
            for (int j = 0; j < 4; ++j)
                acc[i][j] = __builtin_amdgcn_mfma_f32_16x16x32_bf16(a[i], b[j], acc[i][j], 0, 0, 0);
    }
    // C/D layout: col = lane&15, row = (lane>>4)*4 + reg   [m89-verified]
#pragma unroll
    for (int j = 0; j < 4; ++j) {
        int c = cb + 16 * j + l15;
        float bv = bias[c];
#pragma unroll
        for (int i = 0; i < 4; ++i) {
            int rbase = rb + 16 * i + (lane >> 4) * 4;
#pragma unroll
            for (int r = 0; r < 4; ++r) {
                int row = rbase + r;
                if (row < N_NODES) {
                    float v = acc[i][j][r] + bv;
                    if (RELU) v = fmaxf(v, 0.f);
                    out[(long)row * outStride + c] = f2bf(v);
                }
            }
        }
    }
}

// ---------------- MLP head: out[n][j] = sum_k h2[n][k]*Wmlp[k][j] + bmlp[j] ----------------

__global__ __launch_bounds__(256) void head_kernel(const unsigned short* __restrict__ h2,
                                                   const float* __restrict__ Wmlp,
                                                   const float* __restrict__ bmlp,
                                                   float* __restrict__ out) {
    int n = blockIdx.x * 4 + (threadIdx.x >> 6);
    int lane = threadIdx.x & 63;
    const unsigned* p = (const unsigned*)(h2 + (long)n * 256 + lane * 4);
    unsigned v0 = p[0], v1 = p[1];
    float f0 = bf2f(v0 & 0xffffu), f1 = bf2f(v0 >> 16);
    float f2 = bf2f(v1 & 0xffffu), f3 = bf2f(v1 >> 16);
    int k = lane * 4;
    float p0 = f0 * Wmlp[k * 2]       + f1 * Wmlp[(k + 1) * 2]
             + f2 * Wmlp[(k + 2) * 2] + f3 * Wmlp[(k + 3) * 2];
    float p1 = f0 * Wmlp[k * 2 + 1]       + f1 * Wmlp[(k + 1) * 2 + 1]
             + f2 * Wmlp[(k + 2) * 2 + 1] + f3 * Wmlp[(k + 3) * 2 + 1];
    for (int off = 32; off; off >>= 1) {
        p0 += __shfl_down(p0, off);
        p1 += __shfl_down(p1, off);
    }
    if (lane == 0) {
        out[(long)n * 2]     = p0 + bmlp[0];
        out[(long)n * 2 + 1] = p1 + bmlp[1];
    }
}

// ---------------- launch ----------------

extern "C" void kernel_launch(void* const* d_in, const int* in_sizes, int n_in,
                              void* d_out, int out_size, void* d_ws, size_t ws_size,
                              hipStream_t stream) {
    const float* x    = (const float*)d_in[0];
    const int*   src  = (const int*)d_in[1];
    const int*   dst  = (const int*)d_in[2];
    const float* Ws1  = (const float*)d_in[3];
    const float* Wn1  = (const float*)d_in[4];
    const float* b1   = (const float*)d_in[5];
    const float* Ws2  = (const float*)d_in[6];
    const float* Wn2  = (const float*)d_in[7];
    const float* b2   = (const float*)d_in[8];
    const float* Wres = (const float*)d_in[9];
    const float* Wmlp = (const float*)d_in[10];
    const float* bmlp = (const float*)d_in[11];
    float* out = (float*)d_out;

    char* ws = (char*)d_ws;
    size_t off = 0;
    auto alloc = [&](size_t bytes) {
        void* p = ws + off;
        off += (bytes + 255) & ~(size_t)255;
        return p;
    };
    int*            cnt      = (int*)alloc((size_t)N_NODES * 4);
    int*            row_ptr  = (int*)alloc((size_t)(N_NODES + 1) * 4);
    int*            cursor   = (int*)alloc((size_t)N_NODES * 4);
    float*          inv_deg  = (float*)alloc((size_t)N_NODES * 4);
    int*            srcs     = (int*)alloc((size_t)N_EDGES * 4);
    int*            blocksum = (int*)alloc((size_t)SCAN_BLOCKS * 4);
    int*            blockoff = (int*)alloc((size_t)SCAN_BLOCKS * 4);
    unsigned short* A1       = (unsigned short*)alloc((size_t)N_NODES * 256 * 2);  // [x|agg1]; later h2
    unsigned short* A2       = (unsigned short*)alloc((size_t)N_NODES * 640 * 2);  // [h1|agg2|x]
    unsigned short* Wt1      = (unsigned short*)alloc((size_t)256 * 256 * 2);
    unsigned short* Wt2      = (unsigned short*)alloc((size_t)256 * 640 * 2);

    hipMemsetAsync(cnt, 0, (size_t)N_NODES * 4, stream);
    hist_kernel<<<(N_EDGES + 255) / 256, 256, 0, stream>>>(dst, cnt);
    scan1_kernel<<<SCAN_BLOCKS, 256, 0, stream>>>(cnt, blocksum);
    scan2_kernel<<<1, 256, 0, stream>>>(blocksum, blockoff);
    scan3_kernel<<<SCAN_BLOCKS, 256, 0, stream>>>(cnt, blockoff, row_ptr, cursor, inv_deg);
    fill_kernel<<<(N_EDGES + 255) / 256, 256, 0, stream>>>(src, dst, cursor, srcs);
    convx_kernel<<<(N_NODES * D_IN + 255) / 256, 256, 0, stream>>>(x, A1, A2);
    wconv1_kernel<<<256, 256, 0, stream>>>(Ws1, Wn1, Wt1);
    wconv2_kernel<<<256, 256, 0, stream>>>(Ws2, Wn2, Wres, Wt2);
    agg1_kernel<<<N_NODES, 128, 0, stream>>>(x, row_ptr, srcs, inv_deg, A1);

    dim3 ggrid((N_NODES + 127) / 128, 2);
    // layer 1: h1 = relu([x|agg1] @ Wt1^T + b1) -> Acat2 cols [0,256)
    mfma_gemm_kernel<256, true><<<ggrid, 256, 0, stream>>>(A1, Wt1, b1, A2, 640);
    agg2_kernel<<<N_NODES, 128, 0, stream>>>(A2, row_ptr, srcs, inv_deg);
    // layer 2: h2 = [h1|agg2|x] @ Wt2^T + b2 -> A1 (reused as h2 buffer, stride 256)
    mfma_gemm_kernel<640, false><<<ggrid, 256, 0, stream>>>(A2, Wt2, b2, A1, 256);
    head_kernel<<<N_NODES / 4, 256, 0, stream>>>(A1, Wmlp, bmlp, out);
}

// Round 6
// 450.172 us; speedup vs baseline: 2.7127x; 1.0304x over previous
//
#include <hip/hip_runtime.h>

#define N_NODES 50000
#define N_EDGES 800000
#define D_IN 128
#define D_HID 256
#define D_OUT 256

#define SCAN_BLOCKS ((N_NODES + 255) / 256)  // 196

using short8 = __attribute__((ext_vector_type(8))) short;
using f32x4  = __attribute__((ext_vector_type(4))) float;

__device__ inline unsigned short f2bf(float f) {
    unsigned u = __float_as_uint(f);
    u += 0x7fff + ((u >> 16) & 1);
    return (unsigned short)(u >> 16);
}
__device__ inline float bf2f(unsigned v16) {
    return __uint_as_float(v16 << 16);
}

// ---------------- CSR build ----------------

__global__ void hist_kernel(const int* __restrict__ dst, int* __restrict__ cnt) {
    int e = blockIdx.x * blockDim.x + threadIdx.x;
    if (e < N_EDGES) atomicAdd(&cnt[dst[e]], 1);
}

// stage 1: per-block sums of cnt
__global__ __launch_bounds__(256) void scan1_kernel(const int* __restrict__ cnt,
                                                    int* __restrict__ blocksum) {
    int i = blockIdx.x * 256 + threadIdx.x;
    int v = (i < N_NODES) ? cnt[i] : 0;
    int lane = threadIdx.x & 63, wid = threadIdx.x >> 6;
    for (int off = 32; off; off >>= 1) v += __shfl_down(v, off);
    __shared__ int ws[4];
    if (lane == 0) ws[wid] = v;
    __syncthreads();
    if (threadIdx.x == 0) blocksum[blockIdx.x] = ws[0] + ws[1] + ws[2] + ws[3];
}

// stage 2: exclusive scan of the 196 block sums (single block)
__global__ __launch_bounds__(256) void scan2_kernel(const int* __restrict__ blocksum,
                                                    int* __restrict__ blockoff) {
    int tid = threadIdx.x;
    int lane = tid & 63, wid = tid >> 6;
    int v = (tid < SCAN_BLOCKS) ? blocksum[tid] : 0;
    int inc = v;
    for (int off = 1; off < 64; off <<= 1) {
        int u = __shfl_up(inc, off);
        if (lane >= off) inc += u;
    }
    __shared__ int ws[4];
    if (lane == 63) ws[wid] = inc;
    __syncthreads();
    int base = 0;
    for (int w = 0; w < wid; ++w) base += ws[w];
    if (tid < SCAN_BLOCKS) blockoff[tid] = base + inc - v;  // exclusive
}

// stage 3: intra-block exclusive scan + block offset -> row_ptr / cursor / inv_deg
__global__ __launch_bounds__(256) void scan3_kernel(const int* __restrict__ cnt,
                                                    const int* __restrict__ blockoff,
                                                    int* __restrict__ row_ptr,
                                                    int* __restrict__ cursor,
                                                    float* __restrict__ inv_deg) {
    int i = blockIdx.x * 256 + threadIdx.x;
    int c = (i < N_NODES) ? cnt[i] : 0;
    int lane = threadIdx.x & 63, wid = threadIdx.x >> 6;
    int inc = c;
    for (int off = 1; off < 64; off <<= 1) {
        int u = __shfl_up(inc, off);
        if (lane >= off) inc += u;
    }
    __shared__ int ws[4];
    if (lane == 63) ws[wid] = inc;
    __syncthreads();
    int base = blockoff[blockIdx.x];
    for (int w = 0; w < wid; ++w) base += ws[w];
    if (i < N_NODES) {
        int pos = base + inc - c;
        row_ptr[i] = pos;
        cursor[i] = pos;
        inv_deg[i] = 1.0f / (float)max(c, 1);
    }
    if (i == 0) row_ptr[N_NODES] = N_EDGES;
}

__global__ void fill_kernel(const int* __restrict__ src, const int* __restrict__ dst,
                            int* __restrict__ cursor, int* __restrict__ srcs) {
    int e = blockIdx.x * blockDim.x + threadIdx.x;
    if (e < N_EDGES) {
        int pos = atomicAdd(&cursor[dst[e]], 1);
        srcs[pos] = src[e];
    }
}

// ---------------- conversions ----------------

// x (fp32) -> bf16 into Acat1 cols [0,128) and Acat2 cols [512,640)
__global__ void convx_kernel(const float* __restrict__ x,
                             unsigned short* __restrict__ A1,
                             unsigned short* __restrict__ A2) {
    int idx = blockIdx.x * 256 + threadIdx.x;
    if (idx >= N_NODES * D_IN) return;
    int n = idx >> 7, k = idx & 127;
    unsigned short b = f2bf(x[idx]);
    A1[(long)n * 256 + k] = b;
    A2[(long)n * 640 + 512 + k] = b;
}

// Wt1[j][k] (256x256): k<128 -> Ws1[k][j], else Wn1[k-128][j]
__global__ void wconv1_kernel(const float* __restrict__ Ws, const float* __restrict__ Wn,
                              unsigned short* __restrict__ Wt) {
    int j = blockIdx.x;
    for (int k = threadIdx.x; k < 256; k += 256) {
        float v = (k < 128) ? Ws[k * 256 + j] : Wn[(k - 128) * 256 + j];
        Wt[j * 256 + k] = f2bf(v);
    }
}

// Wt2[j][k] (256x640): k<256 Ws2, k<512 Wn2, else Wres
__global__ void wconv2_kernel(const float* __restrict__ Ws, const float* __restrict__ Wn,
                              const float* __restrict__ Wr,
                              unsigned short* __restrict__ Wt) {
    int j = blockIdx.x;
    for (int k = threadIdx.x; k < 640; k += 256) {
        float v = (k < 256) ? Ws[k * 256 + j]
                : (k < 512) ? Wn[(k - 256) * 256 + j]
                            : Wr[(k - 512) * 256 + j];
        Wt[j * 640 + k] = f2bf(v);
    }
}

// ---------------- mean aggregation ----------------

// agg1: gather fp32 x rows, write bf16 into Acat1 cols [128,256)
__global__ void agg1_kernel(const float* __restrict__ x,
                            const int* __restrict__ row_ptr,
                            const int* __restrict__ srcs,
                            const float* __restrict__ inv_deg,
                            unsigned short* __restrict__ A1) {
    int n = blockIdx.x;
    int tid = threadIdx.x;  // 128
    int beg = row_ptr[n], end = row_ptr[n + 1];
    float acc = 0.f;
    int e = beg;
    for (; e + 3 < end; e += 4) {
        int s0 = srcs[e], s1 = srcs[e + 1], s2 = srcs[e + 2], s3 = srcs[e + 3];
        float v0 = x[(long)s0 * D_IN + tid];
        float v1 = x[(long)s1 * D_IN + tid];
        float v2 = x[(long)s2 * D_IN + tid];
        float v3 = x[(long)s3 * D_IN + tid];
        acc += (v0 + v1) + (v2 + v3);
    }
    for (; e < end; ++e) acc += x[(long)srcs[e] * D_IN + tid];
    A1[(long)n * 256 + 128 + tid] = f2bf(acc * inv_deg[n]);
}

// agg2: gather bf16 h1 rows (Acat2 cols [0,256)), write bf16 into Acat2 cols [256,512)
__global__ void agg2_kernel(unsigned short* __restrict__ A2,
                            const int* __restrict__ row_ptr,
                            const int* __restrict__ srcs,
                            const float* __restrict__ inv_deg) {
    int n = blockIdx.x;
    int tid = threadIdx.x;  // 128 threads, 2 cols each
    int beg = row_ptr[n], end = row_ptr[n + 1];
    float a0 = 0.f, a1 = 0.f;
    int e = beg;
    for (; e + 3 < end; e += 4) {
        int s0 = srcs[e], s1 = srcs[e + 1], s2 = srcs[e + 2], s3 = srcs[e + 3];
        unsigned v0 = ((const unsigned*)(A2 + (long)s0 * 640))[tid];
        unsigned v1 = ((const unsigned*)(A2 + (long)s1 * 640))[tid];
        unsigned v2 = ((const unsigned*)(A2 + (long)s2 * 640))[tid];
        unsigned v3 = ((const unsigned*)(A2 + (long)s3 * 640))[tid];
        a0 += (bf2f(v0 & 0xffffu) + bf2f(v1 & 0xffffu)) +
              (bf2f(v2 & 0xffffu) + bf2f(v3 & 0xffffu));
        a1 += (bf2f(v0 >> 16) + bf2f(v1 >> 16)) + (bf2f(v2 >> 16) + bf2f(v3 >> 16));
    }
    for (; e < end; ++e) {
        unsigned v = ((const unsigned*)(A2 + (long)srcs[e] * 640))[tid];
        a0 += bf2f(v & 0xffffu);
        a1 += bf2f(v >> 16);
    }
    float inv = inv_deg[n];
    unsigned o = (unsigned)f2bf(a0 * inv) | ((unsigned)f2bf(a1 * inv) << 16);
    ((unsigned*)(A2 + (long)n * 640 + 256))[tid] = o;
}

// ---------------- MFMA GEMM: out[row][col] = A[row][:] . Bt[col][:] + bias ----------------
// A: [N_NODES][K] bf16, Bt: [256][K] bf16. Block tile 128x128, 4 waves of 64x64.
// K-loop register-double-buffered (2x manual unroll): loads for step t+1 issue
// before the MFMAs of step t, so VMEM latency overlaps MFMA issue.

template <int K, bool RELU>
__global__ __launch_bounds__(256) void mfma_gemm_kernel(
    const unsigned short* __restrict__ A, const unsigned short* __restrict__ Bt,
    const float* __restrict__ bias, unsigned short* __restrict__ out, int outStride) {
    int lane = threadIdx.x & 63;
    int wid = threadIdx.x >> 6;
    int rb = blockIdx.x * 128 + (wid >> 1) * 64;
    int cb = blockIdx.y * 128 + (wid & 1) * 64;
    int l15 = lane & 15;
    int kg = (lane >> 4) * 8;

    // Hoisted row pointers; OOB rows clamp to row 0 (their acc entries are
    // never written, so garbage values are harmless).
    const unsigned short* pA[4];
    const unsigned short* pB[4];
#pragma unroll
    for (int i = 0; i < 4; ++i) {
        int r = rb + 16 * i + l15;
        if (r >= N_NODES) r = 0;
        pA[i] = A + (long)r * K + kg;
        pB[i] = Bt + (long)(cb + 16 * i + l15) * K + kg;
    }

    f32x4 acc[4][4] = {};
    short8 ac[4], bc[4], an[4], bn[4];
#pragma unroll
    for (int i = 0; i < 4; ++i) {
        ac[i] = *(const short8*)(pA[i]);
        bc[i] = *(const short8*)(pB[i]);
    }
    constexpr int NK = K / 32;  // 8 (K=256) or 20 (K=640), always even
#pragma unroll 2
    for (int t = 0; t < NK; t += 2) {
        // prefetch t+1 (always in range since NK is even)
        int k1 = (t + 1) * 32;
#pragma unroll
        for (int i = 0; i < 4; ++i) {
            an[i] = *(const short8*)(pA[i] + k1);
            bn[i] = *(const short8*)(pB[i] + k1);
        }
#pragma unroll
        for (int i = 0; i < 4; ++i)
#pragma unroll
            for (int j = 0; j < 4; ++j)
                acc[i][j] = __builtin_amdgcn_mfma_f32_16x16x32_bf16(ac[i], bc[j], acc[i][j], 0, 0, 0);
        // prefetch t+2
        if (t + 2 < NK) {
            int k2 = (t + 2) * 32;
#pragma unroll
            for (int i = 0; i < 4; ++i) {
                ac[i] = *(const short8*)(pA[i] + k2);
                bc[i] = *(const short8*)(pB[i] + k2);
            }
        }
#pragma unroll
        for (int i = 0; i < 4; ++i)
#pragma unroll
            for (int j = 0; j < 4; ++j)
                acc[i][j] = __builtin_amdgcn_mfma_f32_16x16x32_bf16(an[i], bn[j], acc[i][j], 0, 0, 0);
    }
    // C/D layout: col = lane&15, row = (lane>>4)*4 + reg   [m89-verified]
#pragma unroll
    for (int j = 0; j < 4; ++j) {
        int c = cb + 16 * j + l15;
        float bv = bias[c];
#pragma unroll
        for (int i = 0; i < 4; ++i) {
            int rbase = rb + 16 * i + (lane >> 4) * 4;
#pragma unroll
            for (int r = 0; r < 4; ++r) {
                int row = rbase + r;
                if (row < N_NODES) {
                    float v = acc[i][j][r] + bv;
                    if (RELU) v = fmaxf(v, 0.f);
                    out[(long)row * outStride + c] = f2bf(v);
                }
            }
        }
    }
}

// ---------------- MLP head: out[n][j] = sum_k h2[n][k]*Wmlp[k][j] + bmlp[j] ----------------

__global__ __launch_bounds__(256) void head_kernel(const unsigned short* __restrict__ h2,
                                                   const float* __restrict__ Wmlp,
                                                   const float* __restrict__ bmlp,
                                                   float* __restrict__ out) {
    int n = blockIdx.x * 4 + (threadIdx.x >> 6);
    int lane = threadIdx.x & 63;
    const unsigned* p = (const unsigned*)(h2 + (long)n * 256 + lane * 4);
    unsigned v0 = p[0], v1 = p[1];
    float f0 = bf2f(v0 & 0xffffu), f1 = bf2f(v0 >> 16);
    float f2 = bf2f(v1 & 0xffffu), f3 = bf2f(v1 >> 16);
    int k = lane * 4;
    float p0 = f0 * Wmlp[k * 2]       + f1 * Wmlp[(k + 1) * 2]
             + f2 * Wmlp[(k + 2) * 2] + f3 * Wmlp[(k + 3) * 2];
    float p1 = f0 * Wmlp[k * 2 + 1]       + f1 * Wmlp[(k + 1) * 2 + 1]
             + f2 * Wmlp[(k + 2) * 2 + 1] + f3 * Wmlp[(k + 3) * 2 + 1];
    for (int off = 32; off; off >>= 1) {
        p0 += __shfl_down(p0, off);
        p1 += __shfl_down(p1, off);
    }
    if (lane == 0) {
        out[(long)n * 2]     = p0 + bmlp[0];
        out[(long)n * 2 + 1] = p1 + bmlp[1];
    }
}

// ---------------- launch ----------------

extern "C" void kernel_launch(void* const* d_in, const int* in_sizes, int n_in,
                              void* d_out, int out_size, void* d_ws, size_t ws_size,
                              hipStream_t stream) {
    const float* x    = (const float*)d_in[0];
    const int*   src  = (const int*)d_in[1];
    const int*   dst  = (const int*)d_in[2];
    const float* Ws1  = (const float*)d_in[3];
    const float* Wn1  = (const float*)d_in[4];
    const float* b1   = (const float*)d_in[5];
    const float* Ws2  = (const float*)d_in[6];
    const float* Wn2  = (const float*)d_in[7];
    const float* b2   = (const float*)d_in[8];
    const float* Wres = (const float*)d_in[9];
    const float* Wmlp = (const float*)d_in[10];
    const float* bmlp = (const float*)d_in[11];
    float* out = (float*)d_out;

    char* ws = (char*)d_ws;
    size_t off = 0;
    auto alloc = [&](size_t bytes) {
        void* p = ws + off;
        off += (bytes + 255) & ~(size_t)255;
        return p;
    };
    int*            cnt      = (int*)alloc((size_t)N_NODES * 4);
    int*            row_ptr  = (int*)alloc((size_t)(N_NODES + 1) * 4);
    int*            cursor   = (int*)alloc((size_t)N_NODES * 4);
    float*          inv_deg  = (float*)alloc((size_t)N_NODES * 4);
    int*            srcs     = (int*)alloc((size_t)N_EDGES * 4);
    int*            blocksum = (int*)alloc((size_t)SCAN_BLOCKS * 4);
    int*            blockoff = (int*)alloc((size_t)SCAN_BLOCKS * 4);
    unsigned short* A1       = (unsigned short*)alloc((size_t)N_NODES * 256 * 2);  // [x|agg1]; later h2
    unsigned short* A2       = (unsigned short*)alloc((size_t)N_NODES * 640 * 2);  // [h1|agg2|x]
    unsigned short* Wt1      = (unsigned short*)alloc((size_t)256 * 256 * 2);
    unsigned short* Wt2      = (unsigned short*)alloc((size_t)256 * 640 * 2);

    hipMemsetAsync(cnt, 0, (size_t)N_NODES * 4, stream);
    hist_kernel<<<(N_EDGES + 255) / 256, 256, 0, stream>>>(dst, cnt);
    scan1_kernel<<<SCAN_BLOCKS, 256, 0, stream>>>(cnt, blocksum);
    scan2_kernel<<<1, 256, 0, stream>>>(blocksum, blockoff);
    scan3_kernel<<<SCAN_BLOCKS, 256, 0, stream>>>(cnt, blockoff, row_ptr, cursor, inv_deg);
    fill_kernel<<<(N_EDGES + 255) / 256, 256, 0, stream>>>(src, dst, cursor, srcs);
    convx_kernel<<<(N_NODES * D_IN + 255) / 256, 256, 0, stream>>>(x, A1, A2);
    wconv1_kernel<<<256, 256, 0, stream>>>(Ws1, Wn1, Wt1);
    wconv2_kernel<<<256, 256, 0, stream>>>(Ws2, Wn2, Wres, Wt2);
    agg1_kernel<<<N_NODES, 128, 0, stream>>>(x, row_ptr, srcs, inv_deg, A1);

    dim3 ggrid((N_NODES + 127) / 128, 2);
    // layer 1: h1 = relu([x|agg1] @ Wt1^T + b1) -> Acat2 cols [0,256)
    mfma_gemm_kernel<256, true><<<ggrid, 256, 0, stream>>>(A1, Wt1, b1, A2, 640);
    agg2_kernel<<<N_NODES, 128, 0, stream>>>(A2, row_ptr, srcs, inv_deg);
    // layer 2: h2 = [h1|agg2|x] @ Wt2^T + b2 -> A1 (reused as h2 buffer, stride 256)
    mfma_gemm_kernel<640, false><<<ggrid, 256, 0, stream>>>(A2, Wt2, b2, A1, 256);
    head_kernel<<<N_NODES / 4, 256, 0, stream>>>(A1, Wmlp, bmlp, out);
}

// Round 8
// 429.161 us; speedup vs baseline: 2.8455x; 1.0490x over previous
//
#include <hip/hip_runtime.h>

#define N_NODES 50000
#define N_EDGES 800000
#define D_IN 128
#define D_HID 256
#define D_OUT 256

#define SCAN_BLOCKS ((N_NODES + 255) / 256)  // 196
#define NXB ((N_NODES + 127) / 128)          // 391 row-panels
#define GEMM_GRID (NXB * 4)                  // 1564 blocks (4 col-tiles of 64)

using short8 = __attribute__((ext_vector_type(8))) short;
using f32x4  = __attribute__((ext_vector_type(4))) float;

__device__ inline unsigned short f2bf(float f) {
    unsigned u = __float_as_uint(f);
    u += 0x7fff + ((u >> 16) & 1);
    return (unsigned short)(u >> 16);
}
__device__ inline float bf2f(unsigned v16) {
    return __uint_as_float(v16 << 16);
}

// ---------------- CSR build ----------------

__global__ void hist_kernel(const int* __restrict__ dst, int* __restrict__ cnt) {
    int e = blockIdx.x * blockDim.x + threadIdx.x;
    if (e < N_EDGES) atomicAdd(&cnt[dst[e]], 1);
}

__global__ __launch_bounds__(256) void scan1_kernel(const int* __restrict__ cnt,
                                                    int* __restrict__ blocksum) {
    int i = blockIdx.x * 256 + threadIdx.x;
    int v = (i < N_NODES) ? cnt[i] : 0;
    int lane = threadIdx.x & 63, wid = threadIdx.x >> 6;
    for (int off = 32; off; off >>= 1) v += __shfl_down(v, off);
    __shared__ int ws[4];
    if (lane == 0) ws[wid] = v;
    __syncthreads();
    if (threadIdx.x == 0) blocksum[blockIdx.x] = ws[0] + ws[1] + ws[2] + ws[3];
}

__global__ __launch_bounds__(256) void scan2_kernel(const int* __restrict__ blocksum,
                                                    int* __restrict__ blockoff) {
    int tid = threadIdx.x;
    int lane = tid & 63, wid = tid >> 6;
    int v = (tid < SCAN_BLOCKS) ? blocksum[tid] : 0;
    int inc = v;
    for (int off = 1; off < 64; off <<= 1) {
        int u = __shfl_up(inc, off);
        if (lane >= off) inc += u;
    }
    __shared__ int ws[4];
    if (lane == 63) ws[wid] = inc;
    __syncthreads();
    int base = 0;
    for (int w = 0; w < wid; ++w) base += ws[w];
    if (tid < SCAN_BLOCKS) blockoff[tid] = base + inc - v;  // exclusive
}

__global__ __launch_bounds__(256) void scan3_kernel(const int* __restrict__ cnt,
                                                    const int* __restrict__ blockoff,
                                                    int* __restrict__ row_ptr,
                                                    int* __restrict__ cursor,
                                                    float* __restrict__ inv_deg) {
    int i = blockIdx.x * 256 + threadIdx.x;
    int c = (i < N_NODES) ? cnt[i] : 0;
    int lane = threadIdx.x & 63, wid = threadIdx.x >> 6;
    int inc = c;
    for (int off = 1; off < 64; off <<= 1) {
        int u = __shfl_up(inc, off);
        if (lane >= off) inc += u;
    }
    __shared__ int ws[4];
    if (lane == 63) ws[wid] = inc;
    __syncthreads();
    int base = blockoff[blockIdx.x];
    for (int w = 0; w < wid; ++w) base += ws[w];
    if (i < N_NODES) {
        int pos = base + inc - c;
        row_ptr[i] = pos;
        cursor[i] = pos;
        inv_deg[i] = 1.0f / (float)max(c, 1);
    }
    if (i == 0) row_ptr[N_NODES] = N_EDGES;
}

__global__ void fill_kernel(const int* __restrict__ src, const int* __restrict__ dst,
                            int* __restrict__ cursor, int* __restrict__ srcs) {
    int e = blockIdx.x * blockDim.x + threadIdx.x;
    if (e < N_EDGES) {
        int pos = atomicAdd(&cursor[dst[e]], 1);
        srcs[pos] = src[e];
    }
}

// ---------------- conversions ----------------

__global__ void convx_kernel(const float* __restrict__ x,
                             unsigned short* __restrict__ A1,
                             unsigned short* __restrict__ A2) {
    int idx = blockIdx.x * 256 + threadIdx.x;
    if (idx >= N_NODES * D_IN) return;
    int n = idx >> 7, k = idx & 127;
    unsigned short b = f2bf(x[idx]);
    A1[(long)n * 256 + k] = b;
    A2[(long)n * 640 + 512 + k] = b;
}

__global__ void wconv1_kernel(const float* __restrict__ Ws, const float* __restrict__ Wn,
                              unsigned short* __restrict__ Wt) {
    int j = blockIdx.x;
    for (int k = threadIdx.x; k < 256; k += 256) {
        float v = (k < 128) ? Ws[k * 256 + j] : Wn[(k - 128) * 256 + j];
        Wt[j * 256 + k] = f2bf(v);
    }
}

__global__ void wconv2_kernel(const float* __restrict__ Ws, const float* __restrict__ Wn,
                              const float* __restrict__ Wr,
                              unsigned short* __restrict__ Wt) {
    int j = blockIdx.x;
    for (int k = threadIdx.x; k < 640; k += 256) {
        float v = (k < 256) ? Ws[k * 256 + j]
                : (k < 512) ? Wn[(k - 256) * 256 + j]
                            : Wr[(k - 512) * 256 + j];
        Wt[j * 640 + k] = f2bf(v);
    }
}

// ---------------- mean aggregation ----------------

__global__ void agg1_kernel(const float* __restrict__ x,
                            const int* __restrict__ row_ptr,
                            const int* __restrict__ srcs,
                            const float* __restrict__ inv_deg,
                            unsigned short* __restrict__ A1) {
    int n = blockIdx.x;
    int tid = threadIdx.x;  // 128
    int beg = row_ptr[n], end = row_ptr[n + 1];
    float acc = 0.f;
    int e = beg;
    for (; e + 3 < end; e += 4) {
        int s0 = srcs[e], s1 = srcs[e + 1], s2 = srcs[e + 2], s3 = srcs[e + 3];
        float v0 = x[(long)s0 * D_IN + tid];
        float v1 = x[(long)s1 * D_IN + tid];
        float v2 = x[(long)s2 * D_IN + tid];
        float v3 = x[(long)s3 * D_IN + tid];
        acc += (v0 + v1) + (v2 + v3);
    }
    for (; e < end; ++e) acc += x[(long)srcs[e] * D_IN + tid];
    A1[(long)n * 256 + 128 + tid] = f2bf(acc * inv_deg[n]);
}

__global__ void agg2_kernel(unsigned short* __restrict__ A2,
                            const int* __restrict__ row_ptr,
                            const int* __restrict__ srcs,
                            const float* __restrict__ inv_deg) {
    int n = blockIdx.x;
    int tid = threadIdx.x;  // 128 threads, 2 cols each
    int beg = row_ptr[n], end = row_ptr[n + 1];
    float a0 = 0.f, a1 = 0.f;
    int e = beg;
    for (; e + 3 < end; e += 4) {
        int s0 = srcs[e], s1 = srcs[e + 1], s2 = srcs[e + 2], s3 = srcs[e + 3];
        unsigned v0 = ((const unsigned*)(A2 + (long)s0 * 640))[tid];
        unsigned v1 = ((const unsigned*)(A2 + (long)s1 * 640))[tid];
        unsigned v2 = ((const unsigned*)(A2 + (long)s2 * 640))[tid];
        unsigned v3 = ((const unsigned*)(A2 + (long)s3 * 640))[tid];
        a0 += (bf2f(v0 & 0xffffu) + bf2f(v1 & 0xffffu)) +
              (bf2f(v2 & 0xffffu) + bf2f(v3 & 0xffffu));
        a1 += (bf2f(v0 >> 16) + bf2f(v1 >> 16)) + (bf2f(v2 >> 16) + bf2f(v3 >> 16));
    }
    for (; e < end; ++e) {
        unsigned v = ((const unsigned*)(A2 + (long)srcs[e] * 640))[tid];
        a0 += bf2f(v & 0xffffu);
        a1 += bf2f(v >> 16);
    }
    float inv = inv_deg[n];
    unsigned o = (unsigned)f2bf(a0 * inv) | ((unsigned)f2bf(a1 * inv) << 16);
    ((unsigned*)(A2 + (long)n * 640 + 256))[tid] = o;
}

// ---------------- MFMA GEMM with LDS-staged B ----------------
// out[row][col] = A[row][:] . Bt[col][:] + bias.  A: [N_NODES][K] bf16 (global,
// streamed), Bt: [256][K] bf16 (small, L2-hot -> double-buffered LDS chunks).
// Block: 256 thr = 4 waves; tile 128 rows x 64 cols; wave = 32 rows x 64 cols.
// Grid: NXB row-panels x 4 col-tiles = 1564 blocks (~4 blocks/CU resident,
// LDS 33 KB). Only 2 global A-loads per K-step remain in the inner loop.

template <int K, bool RELU>
__global__ __launch_bounds__(256) void gemm_ldsb_kernel(
    const unsigned short* __restrict__ A, const unsigned short* __restrict__ Bt,
    const float* __restrict__ bias, unsigned short* __restrict__ out, int outStride) {
    constexpr int NC = K / 128;   // K-chunks of 128 (2 or 5)
    constexpr int NT = NC * 4;    // 32-wide K-steps
    constexpr int LDSK = 132;     // 128 + 4 pad (shorts) -> conflict-free ds_read
    __shared__ unsigned short Blds[2][64][LDSK];

    int tid = threadIdx.x;
    int lane = tid & 63, w = tid >> 6;
    // bijective chunked block->XCD remap: 4 consecutive logical blocks share an
    // A-panel; keep them on one XCD's L2. NWG=1564 = 8*195+4 (m204 variant).
    int b = blockIdx.x;
    int xcd = b & 7, slot = b >> 3;
    int l = (xcd < 4) ? xcd * 196 + slot : 4 * 196 + (xcd - 4) * 195 + slot;
    int bx = l >> 2, by = l & 3;

    int rb = bx * 128 + w * 32;
    int cb = by * 64;
    int l15 = lane & 15;
    int kg = (lane >> 4) * 8;

    // A row pointers (2 row-frags per wave); OOB rows clamp to 0 (never stored)
    const unsigned short* pA[2];
#pragma unroll
    for (int i = 0; i < 2; ++i) {
        int r = rb + 16 * i + l15;
        if (r >= N_NODES) r = 0;
        pA[i] = A + (long)r * K + kg;
    }
    // B staging: 64 cols x 128 k = 16 KB/chunk; 256 threads x 4 iters x 16 B.
    // thread t, iter it: q = it*256+t -> col=q>>4, ck=q&15
    const unsigned short* pS[4];
    unsigned short* pW[4];
#pragma unroll
    for (int it = 0; it < 4; ++it) {
        int q = it * 256 + tid;
        int col = q >> 4, ck = q & 15;
        pS[it] = Bt + (long)(cb + col) * K + ck * 8;
        pW[it] = &Blds[0][col][ck * 8];
    }
    constexpr int BUFOFF = 64 * LDSK;

    // prologue: stage chunk 0
    short8 st[4];
#pragma unroll
    for (int it = 0; it < 4; ++it) st[it] = *(const short8*)(pS[it]);
#pragma unroll
    for (int it = 0; it < 4; ++it) *(short8*)(pW[it]) = st[it];
    __syncthreads();

    f32x4 acc[2][4] = {};
    short8 a0[2], a1[2];
#pragma unroll
    for (int i = 0; i < 2; ++i) a0[i] = *(const short8*)(pA[i]);  // step 0

    for (int c = 0; c < NC; ++c) {
        int cur = c & 1;
        const unsigned short* Bb = &Blds[0][0][0] + cur * BUFOFF;
        bool more = (c + 1 < NC);
        // issue next chunk's staging loads early (land during the 4 K-steps)
        if (more) {
#pragma unroll
            for (int it = 0; it < 4; ++it)
                st[it] = *(const short8*)(pS[it] + (c + 1) * 128);
        }
        int t0 = c * 4;
        // ks=0: A-prefetch t0+1 -> a1, compute with a0
        {
#pragma unroll
            for (int i = 0; i < 2; ++i) a1[i] = *(const short8*)(pA[i] + (t0 + 1) * 32);
            short8 bfr[4];
#pragma unroll
            for (int j = 0; j < 4; ++j)
                bfr[j] = *(const short8*)(Bb + (16 * j + l15) * LDSK + 0 * 32 + kg);
#pragma unroll
            for (int i = 0; i < 2; ++i)
#pragma unroll
                for (int j = 0; j < 4; ++j)
                    acc[i][j] = __builtin_amdgcn_mfma_f32_16x16x32_bf16(a0[i], bfr[j], acc[i][j], 0, 0, 0);
        }
        // ks=1: prefetch t0+2 -> a0, compute with a1
        {
#pragma unroll
            for (int i = 0; i < 2; ++i) a0[i] = *(const short8*)(pA[i] + (t0 + 2) * 32);
            short8 bfr[4];
#pragma unroll
            for (int j = 0; j < 4; ++j)
                bfr[j] = *(const short8*)(Bb + (16 * j + l15) * LDSK + 1 * 32 + kg);
#pragma unroll
            for (int i = 0; i < 2; ++i)
#pragma unroll
                for (int j = 0; j < 4; ++j)
                    acc[i][j] = __builtin_amdgcn_mfma_f32_16x16x32_bf16(a1[i], bfr[j], acc[i][j], 0, 0, 0);
        }
        // ks=2: prefetch t0+3 -> a1, compute with a0
        {
#pragma unroll
            for (int i = 0; i < 2; ++i) a1[i] = *(const short8*)(pA[i] + (t0 + 3) * 32);
            short8 bfr[4];
#pragma unroll
            for (int j = 0; j < 4; ++j)
                bfr[j] = *(const short8*)(Bb + (16 * j + l15) * LDSK + 2 * 32 + kg);
#pragma unroll
            for (int i = 0; i < 2; ++i)
#pragma unroll
                for (int j = 0; j < 4; ++j)
                    acc[i][j] = __builtin_amdgcn_mfma_f32_16x16x32_bf16(a0[i], bfr[j], acc[i][j], 0, 0, 0);
        }
        // ks=3: prefetch next chunk's step -> a0 (guarded), compute with a1
        {
            if (t0 + 4 < NT) {
#pragma unroll
                for (int i = 0; i < 2; ++i) a0[i] = *(const short8*)(pA[i] + (t0 + 4) * 32);
            }
            short8 bfr[4];
#pragma unroll
            for (int j = 0; j < 4; ++j)
                bfr[j] = *(const short8*)(Bb + (16 * j + l15) * LDSK + 3 * 32 + kg);
#pragma unroll
            for (int i = 0; i < 2; ++i)
#pragma unroll
                for (int j = 0; j < 4; ++j)
                    acc[i][j] = __builtin_amdgcn_mfma_f32_16x16x32_bf16(a1[i], bfr[j], acc[i][j], 0, 0, 0);
        }
        __syncthreads();
        if (more) {
#pragma unroll
            for (int it = 0; it < 4; ++it)
                *(short8*)(pW[it] + ((c + 1) & 1) * BUFOFF) = st[it];
        }
        __syncthreads();
    }

    // C/D layout: col = lane&15, row = (lane>>4)*4 + reg   [m89-verified]
#pragma unroll
    for (int j = 0; j < 4; ++j) {
        int c = cb + 16 * j + l15;
        float bv = bias[c];
#pragma unroll
        for (int i = 0; i < 2; ++i) {
            int rbase = rb + 16 * i + (lane >> 4) * 4;
#pragma unroll
            for (int r = 0; r < 4; ++r) {
                int row = rbase + r;
                if (row < N_NODES) {
                    float v = acc[i][j][r] + bv;
                    if (RELU) v = fmaxf(v, 0.f);
                    out[(long)row * outStride + c] = f2bf(v);
                }
            }
        }
    }
}

// ---------------- MLP head ----------------

__global__ __launch_bounds__(256) void head_kernel(const unsigned short* __restrict__ h2,
                                                   const float* __restrict__ Wmlp,
                                                   const float* __restrict__ bmlp,
                                                   float* __restrict__ out) {
    int n = blockIdx.x * 4 + (threadIdx.x >> 6);
    int lane = threadIdx.x & 63;
    const unsigned* p = (const unsigned*)(h2 + (long)n * 256 + lane * 4);
    unsigned v0 = p[0], v1 = p[1];
    float f0 = bf2f(v0 & 0xffffu), f1 = bf2f(v0 >> 16);
    float f2 = bf2f(v1 & 0xffffu), f3 = bf2f(v1 >> 16);
    int k = lane * 4;
    float p0 = f0 * Wmlp[k * 2]       + f1 * Wmlp[(k + 1) * 2]
             + f2 * Wmlp[(k + 2) * 2] + f3 * Wmlp[(k + 3) * 2];
    float p1 = f0 * Wmlp[k * 2 + 1]       + f1 * Wmlp[(k + 1) * 2 + 1]
             + f2 * Wmlp[(k + 2) * 2 + 1] + f3 * Wmlp[(k + 3) * 2 + 1];
    for (int off = 32; off; off >>= 1) {
        p0 += __shfl_down(p0, off);
        p1 += __shfl_down(p1, off);
    }
    if (lane == 0) {
        out[(long)n * 2]     = p0 + bmlp[0];
        out[(long)n * 2 + 1] = p1 + bmlp[1];
    }
}

// ---------------- launch ----------------

extern "C" void kernel_launch(void* const* d_in, const int* in_sizes, int n_in,
                              void* d_out, int out_size, void* d_ws, size_t ws_size,
                              hipStream_t stream) {
    const float* x    = (const float*)d_in[0];
    const int*   src  = (const int*)d_in[1];
    const int*   dst  = (const int*)d_in[2];
    const float* Ws1  = (const float*)d_in[3];
    const float* Wn1  = (const float*)d_in[4];
    const float* b1   = (const float*)d_in[5];
    const float* Ws2  = (const float*)d_in[6];
    const float* Wn2  = (const float*)d_in[7];
    const float* b2   = (const float*)d_in[8];
    const float* Wres = (const float*)d_in[9];
    const float* Wmlp = (const float*)d_in[10];
    const float* bmlp = (const float*)d_in[11];
    float* out = (float*)d_out;

    char* ws = (char*)d_ws;
    size_t off = 0;
    auto alloc = [&](size_t bytes) {
        void* p = ws + off;
        off += (bytes + 255) & ~(size_t)255;
        return p;
    };
    int*            cnt      = (int*)alloc((size_t)N_NODES * 4);
    int*            row_ptr  = (int*)alloc((size_t)(N_NODES + 1) * 4);
    int*            cursor   = (int*)alloc((size_t)N_NODES * 4);
    float*          inv_deg  = (float*)alloc((size_t)N_NODES * 4);
    int*            srcs     = (int*)alloc((size_t)N_EDGES * 4);
    int*            blocksum = (int*)alloc((size_t)SCAN_BLOCKS * 4);
    int*            blockoff = (int*)alloc((size_t)SCAN_BLOCKS * 4);
    unsigned short* A1       = (unsigned short*)alloc((size_t)N_NODES * 256 * 2);  // [x|agg1]; later h2
    unsigned short* A2       = (unsigned short*)alloc((size_t)N_NODES * 640 * 2);  // [h1|agg2|x]
    unsigned short* Wt1      = (unsigned short*)alloc((size_t)256 * 256 * 2);
    unsigned short* Wt2      = (unsigned short*)alloc((size_t)256 * 640 * 2);

    hipMemsetAsync(cnt, 0, (size_t)N_NODES * 4, stream);
    hist_kernel<<<(N_EDGES + 255) / 256, 256, 0, stream>>>(dst, cnt);
    scan1_kernel<<<SCAN_BLOCKS, 256, 0, stream>>>(cnt, blocksum);
    scan2_kernel<<<1, 256, 0, stream>>>(blocksum, blockoff);
    scan3_kernel<<<SCAN_BLOCKS, 256, 0, stream>>>(cnt, blockoff, row_ptr, cursor, inv_deg);
    fill_kernel<<<(N_EDGES + 255) / 256, 256, 0, stream>>>(src, dst, cursor, srcs);
    convx_kernel<<<(N_NODES * D_IN + 255) / 256, 256, 0, stream>>>(x, A1, A2);
    wconv1_kernel<<<256, 256, 0, stream>>>(Ws1, Wn1, Wt1);
    wconv2_kernel<<<256, 256, 0, stream>>>(Ws2, Wn2, Wres, Wt2);
    agg1_kernel<<<N_NODES, 128, 0, stream>>>(x, row_ptr, srcs, inv_deg, A1);

    // layer 1: h1 = relu([x|agg1] @ Wt1^T + b1) -> Acat2 cols [0,256)
    gemm_ldsb_kernel<256, true><<<GEMM_GRID, 256, 0, stream>>>(A1, Wt1, b1, A2, 640);
    agg2_kernel<<<N_NODES, 128, 0, stream>>>(A2, row_ptr, srcs, inv_deg);
    // layer 2: h2 = [h1|agg2|x] @ Wt2^T + b2 -> A1 (reused as h2 buffer, stride 256)
    gemm_ldsb_kernel<640, false><<<GEMM_GRID, 256, 0, stream>>>(A2, Wt2, b2, A1, 256);
    head_kernel<<<N_NODES / 4, 256, 0, stream>>>(A1, Wmlp, bmlp, out);
}

// Round 10
// 414.478 us; speedup vs baseline: 2.9463x; 1.0354x over previous
//
#include <hip/hip_runtime.h>

#define N_NODES 50000
#define N_EDGES 800000
#define D_IN 128
#define D_HID 256
#define D_OUT 256

#define SCAN_BLOCKS ((N_NODES + 255) / 256)  // 196
#define NXB ((N_NODES + 127) / 128)          // 391 row-panels
#define GEMM_GRID (NXB * 4)                  // 1564 blocks (4 col-tiles of 64)

using short8 = __attribute__((ext_vector_type(8))) short;
using f32x4  = __attribute__((ext_vector_type(4))) float;

__device__ inline unsigned short f2bf(float f) {
    unsigned u = __float_as_uint(f);
    u += 0x7fff + ((u >> 16) & 1);
    return (unsigned short)(u >> 16);
}
__device__ inline float bf2f(unsigned v16) {
    return __uint_as_float(v16 << 16);
}

// ---------------- CSR build ----------------

__global__ void hist_kernel(const int* __restrict__ dst, int* __restrict__ cnt) {
    int e = blockIdx.x * blockDim.x + threadIdx.x;
    if (e < N_EDGES) atomicAdd(&cnt[dst[e]], 1);
}

__global__ __launch_bounds__(256) void scan1_kernel(const int* __restrict__ cnt,
                                                    int* __restrict__ blocksum) {
    int i = blockIdx.x * 256 + threadIdx.x;
    int v = (i < N_NODES) ? cnt[i] : 0;
    int lane = threadIdx.x & 63, wid = threadIdx.x >> 6;
    for (int off = 32; off; off >>= 1) v += __shfl_down(v, off);
    __shared__ int ws[4];
    if (lane == 0) ws[wid] = v;
    __syncthreads();
    if (threadIdx.x == 0) blocksum[blockIdx.x] = ws[0] + ws[1] + ws[2] + ws[3];
}

__global__ __launch_bounds__(256) void scan2_kernel(const int* __restrict__ blocksum,
                                                    int* __restrict__ blockoff) {
    int tid = threadIdx.x;
    int lane = tid & 63, wid = tid >> 6;
    int v = (tid < SCAN_BLOCKS) ? blocksum[tid] : 0;
    int inc = v;
    for (int off = 1; off < 64; off <<= 1) {
        int u = __shfl_up(inc, off);
        if (lane >= off) inc += u;
    }
    __shared__ int ws[4];
    if (lane == 63) ws[wid] = inc;
    __syncthreads();
    int base = 0;
    for (int w = 0; w < wid; ++w) base += ws[w];
    if (tid < SCAN_BLOCKS) blockoff[tid] = base + inc - v;  // exclusive
}

__global__ __launch_bounds__(256) void scan3_kernel(const int* __restrict__ cnt,
                                                    const int* __restrict__ blockoff,
                                                    int* __restrict__ row_ptr,
                                                    int* __restrict__ cursor,
                                                    float* __restrict__ inv_deg) {
    int i = blockIdx.x * 256 + threadIdx.x;
    int c = (i < N_NODES) ? cnt[i] : 0;
    int lane = threadIdx.x & 63, wid = threadIdx.x >> 6;
    int inc = c;
    for (int off = 1; off < 64; off <<= 1) {
        int u = __shfl_up(inc, off);
        if (lane >= off) inc += u;
    }
    __shared__ int ws[4];
    if (lane == 63) ws[wid] = inc;
    __syncthreads();
    int base = blockoff[blockIdx.x];
    for (int w = 0; w < wid; ++w) base += ws[w];
    if (i < N_NODES) {
        int pos = base + inc - c;
        row_ptr[i] = pos;
        cursor[i] = pos;
        inv_deg[i] = 1.0f / (float)max(c, 1);
    }
    if (i == 0) row_ptr[N_NODES] = N_EDGES;
}

__global__ void fill_kernel(const int* __restrict__ src, const int* __restrict__ dst,
                            int* __restrict__ cursor, int* __restrict__ srcs) {
    int e = blockIdx.x * blockDim.x + threadIdx.x;
    if (e < N_EDGES) {
        int pos = atomicAdd(&cursor[dst[e]], 1);
        srcs[pos] = src[e];
    }
}

// ---------------- conversions ----------------

__global__ void convx_kernel(const float* __restrict__ x,
                             unsigned short* __restrict__ A1,
                             unsigned short* __restrict__ A2) {
    int idx = blockIdx.x * 256 + threadIdx.x;
    if (idx >= N_NODES * D_IN) return;
    int n = idx >> 7, k = idx & 127;
    unsigned short b = f2bf(x[idx]);
    A1[(long)n * 256 + k] = b;
    A2[(long)n * 640 + 512 + k] = b;
}

__global__ void wconv1_kernel(const float* __restrict__ Ws, const float* __restrict__ Wn,
                              unsigned short* __restrict__ Wt) {
    int j = blockIdx.x;
    for (int k = threadIdx.x; k < 256; k += 256) {
        float v = (k < 128) ? Ws[k * 256 + j] : Wn[(k - 128) * 256 + j];
        Wt[j * 256 + k] = f2bf(v);
    }
}

__global__ void wconv2_kernel(const float* __restrict__ Ws, const float* __restrict__ Wn,
                              const float* __restrict__ Wr,
                              unsigned short* __restrict__ Wt) {
    int j = blockIdx.x;
    for (int k = threadIdx.x; k < 640; k += 256) {
        float v = (k < 256) ? Ws[k * 256 + j]
                : (k < 512) ? Wn[(k - 256) * 256 + j]
                            : Wr[(k - 512) * 256 + j];
        Wt[j * 640 + k] = f2bf(v);
    }
}

// ---------------- mean aggregation ----------------

// agg1: gather bf16 x rows from A1 cols [0,128) (256 B/row footprint vs 512 B
// for fp32 -> better L2/L3 hit rate), write bf16 into A1 cols [128,256)
__global__ void agg1_kernel(const int* __restrict__ row_ptr,
                            const int* __restrict__ srcs,
                            const float* __restrict__ inv_deg,
                            unsigned short* __restrict__ A1) {
    int n = blockIdx.x;
    int tid = threadIdx.x;  // 128
    int beg = row_ptr[n], end = row_ptr[n + 1];
    float acc = 0.f;
    int e = beg;
    for (; e + 3 < end; e += 4) {
        int s0 = srcs[e], s1 = srcs[e + 1], s2 = srcs[e + 2], s3 = srcs[e + 3];
        unsigned v0 = A1[(long)s0 * 256 + tid];
        unsigned v1 = A1[(long)s1 * 256 + tid];
        unsigned v2 = A1[(long)s2 * 256 + tid];
        unsigned v3 = A1[(long)s3 * 256 + tid];
        acc += (bf2f(v0) + bf2f(v1)) + (bf2f(v2) + bf2f(v3));
    }
    for (; e < end; ++e) acc += bf2f((unsigned)A1[(long)srcs[e] * 256 + tid]);
    A1[(long)n * 256 + 128 + tid] = f2bf(acc * inv_deg[n]);
}

__global__ void agg2_kernel(unsigned short* __restrict__ A2,
                            const int* __restrict__ row_ptr,
                            const int* __restrict__ srcs,
                            const float* __restrict__ inv_deg) {
    int n = blockIdx.x;
    int tid = threadIdx.x;  // 128 threads, 2 cols each
    int beg = row_ptr[n], end = row_ptr[n + 1];
    float a0 = 0.f, a1 = 0.f;
    int e = beg;
    for (; e + 3 < end; e += 4) {
        int s0 = srcs[e], s1 = srcs[e + 1], s2 = srcs[e + 2], s3 = srcs[e + 3];
        unsigned v0 = ((const unsigned*)(A2 + (long)s0 * 640))[tid];
        unsigned v1 = ((const unsigned*)(A2 + (long)s1 * 640))[tid];
        unsigned v2 = ((const unsigned*)(A2 + (long)s2 * 640))[tid];
        unsigned v3 = ((const unsigned*)(A2 + (long)s3 * 640))[tid];
        a0 += (bf2f(v0 & 0xffffu) + bf2f(v1 & 0xffffu)) +
              (bf2f(v2 & 0xffffu) + bf2f(v3 & 0xffffu));
        a1 += (bf2f(v0 >> 16) + bf2f(v1 >> 16)) + (bf2f(v2 >> 16) + bf2f(v3 >> 16));
    }
    for (; e < end; ++e) {
        unsigned v = ((const unsigned*)(A2 + (long)srcs[e] * 640))[tid];
        a0 += bf2f(v & 0xffffu);
        a1 += bf2f(v >> 16);
    }
    float inv = inv_deg[n];
    unsigned o = (unsigned)f2bf(a0 * inv) | ((unsigned)f2bf(a1 * inv) << 16);
    ((unsigned*)(A2 + (long)n * 640 + 256))[tid] = o;
}

// ---------------- MFMA GEMM: LDS-staged B + chunk-pipelined A registers ------
// out[row][col] = A[row][:] . Bt[col][:] + bias.
// Block: 256 thr = 4 waves; tile 128 rows x 64 cols; wave = 32 rows x 64 cols.
// Per 128-wide K-chunk: ALL 8 A-frags of chunk c+1 prefetch into the alternate
// named register buffer (aA/aB) while chunk c's 32 MFMAs execute -> load->use
// distance ~300 cy (vs ~40 cy at depth-1), covering L2/L3 latency.
// B double-buffered in LDS (33 KB -> 4 blocks/CU).

template <int K, bool RELU>
__global__ __launch_bounds__(256) void gemm_ldsb_kernel(
    const unsigned short* __restrict__ A, const unsigned short* __restrict__ Bt,
    const float* __restrict__ bias, unsigned short* __restrict__ out, int outStride) {
    constexpr int NC = K / 128;   // K-chunks of 128 (2 or 5)
    constexpr int LDSK = 132;     // 128 + 4 pad (shorts) -> conflict-free ds_read
    __shared__ unsigned short Blds[2][64][LDSK];

    int tid = threadIdx.x;
    int lane = tid & 63, w = tid >> 6;
    // bijective chunked block->XCD remap: 4 consecutive logical blocks share an
    // A-panel; keep them on one XCD's L2. NWG=1564 = 8*195+4 (m204 variant).
    int b = blockIdx.x;
    int xcd = b & 7, slot = b >> 3;
    int l = (xcd < 4) ? xcd * 196 + slot : 4 * 196 + (xcd - 4) * 195 + slot;
    int bx = l >> 2, by = l & 3;

    int rb = bx * 128 + w * 32;
    int cb = by * 64;
    int l15 = lane & 15;
    int kg = (lane >> 4) * 8;

    // A row pointers (2 row-frags per wave); OOB rows clamp to 0 (never stored)
    const unsigned short* pA[2];
#pragma unroll
    for (int i = 0; i < 2; ++i) {
        int r = rb + 16 * i + l15;
        if (r >= N_NODES) r = 0;
        pA[i] = A + (long)r * K + kg;
    }
    // B staging: 64 cols x 128 k = 16 KB/chunk; 256 threads x 4 iters x 16 B.
    const unsigned short* pS[4];
    unsigned short* pW[4];
#pragma unroll
    for (int it = 0; it < 4; ++it) {
        int q = it * 256 + tid;
        int col = q >> 4, ck = q & 15;
        pS[it] = Bt + (long)(cb + col) * K + ck * 8;
        pW[it] = &Blds[0][col][ck * 8];
    }
    constexpr int BUFOFF = 64 * LDSK;

    f32x4 acc[2][4] = {};
    short8 st[4];
    short8 aA[8], aB[8];  // two chunk-sized A register buffers (static indexing only)

    auto stageIssue = [&](int cc) {
#pragma unroll
        for (int it = 0; it < 4; ++it) st[it] = *(const short8*)(pS[it] + cc * 128);
    };
    auto stageWrite = [&](int buf) {
#pragma unroll
        for (int it = 0; it < 4; ++it) *(short8*)(pW[it] + buf * BUFOFF) = st[it];
    };
    auto loadChunk = [&](short8 (&dst)[8], int cc) {
#pragma unroll
        for (int i = 0; i < 2; ++i)
#pragma unroll
            for (int t = 0; t < 4; ++t)
                dst[i * 4 + t] = *(const short8*)(pA[i] + (cc * 4 + t) * 32);
    };
    auto computeChunk = [&](const short8 (&areg)[8], int buf) {
        const unsigned short* Bb = &Blds[0][0][0] + buf * BUFOFF;
#pragma unroll
        for (int t = 0; t < 4; ++t) {
            short8 bfr[4];
#pragma unroll
            for (int j = 0; j < 4; ++j)
                bfr[j] = *(const short8*)(Bb + (16 * j + l15) * LDSK + t * 32 + kg);
#pragma unroll
            for (int i = 0; i < 2; ++i)
#pragma unroll
                for (int j = 0; j < 4; ++j)
                    acc[i][j] = __builtin_amdgcn_mfma_f32_16x16x32_bf16(
                        areg[i * 4 + t], bfr[j], acc[i][j], 0, 0, 0);
        }
    };

    // prologue: stage B chunk 0, load A chunk 0
    stageIssue(0);
    stageWrite(0);
    loadChunk(aA, 0);
    __syncthreads();

    int c = 0;
    while (c + 2 <= NC) {
        // chunk c (aA); prefetch c+1 (B-stage + aB)
        stageIssue(c + 1);
        loadChunk(aB, c + 1);
        computeChunk(aA, c & 1);
        __syncthreads();
        stageWrite((c + 1) & 1);
        __syncthreads();
        // chunk c+1 (aB); prefetch c+2 (if any)
        if (c + 2 < NC) {
            stageIssue(c + 2);
            loadChunk(aA, c + 2);
        }
        computeChunk(aB, (c + 1) & 1);
        __syncthreads();
        if (c + 2 < NC) stageWrite((c + 2) & 1);
        __syncthreads();
        c += 2;
    }
    if (c < NC) computeChunk(aA, c & 1);  // odd-NC tail (chunk already prefetched)

    // C/D layout: col = lane&15, row = (lane>>4)*4 + reg   [m89-verified]
#pragma unroll
    for (int j = 0; j < 4; ++j) {
        int cc = cb + 16 * j + l15;
        float bv = bias[cc];
#pragma unroll
        for (int i = 0; i < 2; ++i) {
            int rbase = rb + 16 * i + (lane >> 4) * 4;
#pragma unroll
            for (int r = 0; r < 4; ++r) {
                int row = rbase + r;
                if (row < N_NODES) {
                    float v = acc[i][j][r] + bv;
                    if (RELU) v = fmaxf(v, 0.f);
                    out[(long)row * outStride + cc] = f2bf(v);
                }
            }
        }
    }
}

// ---------------- MLP head ----------------

__global__ __launch_bounds__(256) void head_kernel(const unsigned short* __restrict__ h2,
                                                   const float* __restrict__ Wmlp,
                                                   const float* __restrict__ bmlp,
                                                   float* __restrict__ out) {
    int n = blockIdx.x * 4 + (threadIdx.x >> 6);
    int lane = threadIdx.x & 63;
    const unsigned* p = (const unsigned*)(h2 + (long)n * 256 + lane * 4);
    unsigned v0 = p[0], v1 = p[1];
    float f0 = bf2f(v0 & 0xffffu), f1 = bf2f(v0 >> 16);
    float f2 = bf2f(v1 & 0xffffu), f3 = bf2f(v1 >> 16);
    int k = lane * 4;
    float p0 = f0 * Wmlp[k * 2]       + f1 * Wmlp[(k + 1) * 2]
             + f2 * Wmlp[(k + 2) * 2] + f3 * Wmlp[(k + 3) * 2];
    float p1 = f0 * Wmlp[k * 2 + 1]       + f1 * Wmlp[(k + 1) * 2 + 1]
             + f2 * Wmlp[(k + 2) * 2 + 1] + f3 * Wmlp[(k + 3) * 2 + 1];
    for (int off = 32; off; off >>= 1) {
        p0 += __shfl_down(p0, off);
        p1 += __shfl_down(p1, off);
    }
    if (lane == 0) {
        out[(long)n * 2]     = p0 + bmlp[0];
        out[(long)n * 2 + 1] = p1 + bmlp[1];
    }
}

// ---------------- launch ----------------

extern "C" void kernel_launch(void* const* d_in, const int* in_sizes, int n_in,
                              void* d_out, int out_size, void* d_ws, size_t ws_size,
                              hipStream_t stream) {
    const float* x    = (const float*)d_in[0];
    const int*   src  = (const int*)d_in[1];
    const int*   dst  = (const int*)d_in[2];
    const float* Ws1  = (const float*)d_in[3];
    const float* Wn1  = (const float*)d_in[4];
    const float* b1   = (const float*)d_in[5];
    const float* Ws2  = (const float*)d_in[6];
    const float* Wn2  = (const float*)d_in[7];
    const float* b2   = (const float*)d_in[8];
    const float* Wres = (const float*)d_in[9];
    const float* Wmlp = (const float*)d_in[10];
    const float* bmlp = (const float*)d_in[11];
    float* out = (float*)d_out;

    char* ws = (char*)d_ws;
    size_t off = 0;
    auto alloc = [&](size_t bytes) {
        void* p = ws + off;
        off += (bytes + 255) & ~(size_t)255;
        return p;
    };
    int*            cnt      = (int*)alloc((size_t)N_NODES * 4);
    int*            row_ptr  = (int*)alloc((size_t)(N_NODES + 1) * 4);
    int*            cursor   = (int*)alloc((size_t)N_NODES * 4);
    float*          inv_deg  = (float*)alloc((size_t)N_NODES * 4);
    int*            srcs     = (int*)alloc((size_t)N_EDGES * 4);
    int*            blocksum = (int*)alloc((size_t)SCAN_BLOCKS * 4);
    int*            blockoff = (int*)alloc((size_t)SCAN_BLOCKS * 4);
    unsigned short* A1       = (unsigned short*)alloc((size_t)N_NODES * 256 * 2);  // [x|agg1]; later h2
    unsigned short* A2       = (unsigned short*)alloc((size_t)N_NODES * 640 * 2);  // [h1|agg2|x]
    unsigned short* Wt1      = (unsigned short*)alloc((size_t)256 * 256 * 2);
    unsigned short* Wt2      = (unsigned short*)alloc((size_t)256 * 640 * 2);

    hipMemsetAsync(cnt, 0, (size_t)N_NODES * 4, stream);
    hist_kernel<<<(N_EDGES + 255) / 256, 256, 0, stream>>>(dst, cnt);
    scan1_kernel<<<SCAN_BLOCKS, 256, 0, stream>>>(cnt, blocksum);
    scan2_kernel<<<1, 256, 0, stream>>>(blocksum, blockoff);
    scan3_kernel<<<SCAN_BLOCKS, 256, 0, stream>>>(cnt, blockoff, row_ptr, cursor, inv_deg);
    fill_kernel<<<(N_EDGES + 255) / 256, 256, 0, stream>>>(src, dst, cursor, srcs);
    convx_kernel<<<(N_NODES * D_IN + 255) / 256, 256, 0, stream>>>(x, A1, A2);
    wconv1_kernel<<<256, 256, 0, stream>>>(Ws1, Wn1, Wt1);
    wconv2_kernel<<<256, 256, 0, stream>>>(Ws2, Wn2, Wres, Wt2);
    agg1_kernel<<<N_NODES, 128, 0, stream>>>(row_ptr, srcs, inv_deg, A1);

    // layer 1: h1 = relu([x|agg1] @ Wt1^T + b1) -> Acat2 cols [0,256)
    gemm_ldsb_kernel<256, true><<<GEMM_GRID, 256, 0, stream>>>(A1, Wt1, b1, A2, 640);
    agg2_kernel<<<N_NODES, 128, 0, stream>>>(A2, row_ptr, srcs, inv_deg);
    // layer 2: h2 = [h1|agg2|x] @ Wt2^T + b2 -> A1 (reused as h2 buffer, stride 256)
    gemm_ldsb_kernel<640, false><<<GEMM_GRID, 256, 0, stream>>>(A2, Wt2, b2, A1, 256);
    head_kernel<<<N_NODES / 4, 256, 0, stream>>>(A1, Wmlp, bmlp, out);
}